// Round 1
// baseline (429.135 us; speedup 1.0000x reference)
//
#include <hip/hip_runtime.h>

#define B_ 4
#define M_ 5
#define N_ 1000
#define FIN 64
#define H_ 4
#define D_ 64
#define HD 256
#define SH 128
#define OUTD 5
#define NPAD 1024
#define THRESH_ 0.97f

// ---------------------------------------------------------------------------
// Build transposed edge mask: maskT[b,m,d,s] = (adj[b,m,s,d] > THRESH) && s<nn && d<nn
// Shared by both layers. 64x64 tiles through LDS for coalesced read+write.
// ---------------------------------------------------------------------------
__global__ __launch_bounds__(256) void build_maskT(const float* __restrict__ adj,
                                                   const int* __restrict__ node_nums,
                                                   unsigned char* __restrict__ maskT) {
  int bm = blockIdx.z;
  int b = bm / M_;
  int s0 = blockIdx.x * 64, d0 = blockIdx.y * 64;
  int nn = node_nums[b];
  __shared__ unsigned char tile[64][65];
  const float* arow = adj + (size_t)bm * N_ * N_;
  int tid = threadIdx.x;
#pragma unroll
  for (int k = 0; k < 16; ++k) {
    int idx = k * 256 + tid;
    int sl = idx >> 6, dl = idx & 63;
    int s = s0 + sl, d = d0 + dl;
    unsigned char v = 0;
    if (s < nn && d < nn && s < N_ && d < N_)
      v = (arow[(size_t)s * N_ + d] > THRESH_) ? 1 : 0;
    tile[sl][dl] = v;
  }
  __syncthreads();
#pragma unroll
  for (int k = 0; k < 16; ++k) {
    int idx = k * 256 + tid;
    int dl = idx >> 6, sl = idx & 63;
    int d = d0 + dl, s = s0 + sl;
    if (d < N_)
      maskT[((size_t)bm * N_ + d) * NPAD + s] = tile[sl][dl];
  }
}

// ---------------------------------------------------------------------------
// Generic fp32 tiled GEMM: C[z] = A[z] @ B[z]  (64x64 tile, 4x4 microtile)
// b = z / Mz, m = z % Mz;  A += b*aZstride, B += m*bZstride, C += z*cZstride
// mode 1: C = tanh(C + bias[col])
// ---------------------------------------------------------------------------
__global__ __launch_bounds__(256) void gemm64(
    const float* __restrict__ A, int lda, int Mz, size_t aZstride,
    const float* __restrict__ Bw, size_t bZstride,
    float* __restrict__ C, size_t cZstride,
    int Mrows, int K, int ldbc, int mode, const float* __restrict__ bias) {
  __shared__ float As[16][64];
  __shared__ float Bs[16][64];
  int z = blockIdx.z;
  const float* Ab = A + (size_t)(z / Mz) * aZstride;
  const float* Bb = Bw + (size_t)(z % Mz) * bZstride;
  float* Cb = C + (size_t)z * cZstride;
  int row0 = blockIdx.x * 64, col0 = blockIdx.y * 64;
  int tid = threadIdx.x;
  int tx = tid & 15, ty = tid >> 4;
  float acc[4][4] = {};
  int am = tid >> 2, akq = (tid & 3) * 4;
  int bk = tid >> 4, bnq = (tid & 15) * 4;
  for (int k0 = 0; k0 < K; k0 += 16) {
    float4 av;
    int gr = row0 + am;
    if (gr < Mrows)
      av = *(const float4*)(Ab + (size_t)gr * lda + k0 + akq);
    else
      av = make_float4(0.f, 0.f, 0.f, 0.f);
    As[akq + 0][am] = av.x;
    As[akq + 1][am] = av.y;
    As[akq + 2][am] = av.z;
    As[akq + 3][am] = av.w;
    float4 bv = *(const float4*)(Bb + (size_t)(k0 + bk) * ldbc + col0 + bnq);
    *(float4*)&Bs[bk][bnq] = bv;
    __syncthreads();
#pragma unroll
    for (int kk = 0; kk < 16; ++kk) {
      float a0[4], b0[4];
      *(float4*)a0 = *(const float4*)&As[kk][ty * 4];
      *(float4*)b0 = *(const float4*)&Bs[kk][tx * 4];
#pragma unroll
      for (int i = 0; i < 4; ++i)
#pragma unroll
        for (int j = 0; j < 4; ++j) acc[i][j] += a0[i] * b0[j];
    }
    __syncthreads();
  }
#pragma unroll
  for (int i = 0; i < 4; ++i) {
    int gr = row0 + ty * 4 + i;
    if (gr >= Mrows) continue;
    float4 vv;
    float* vp = (float*)&vv;
#pragma unroll
    for (int j = 0; j < 4; ++j) {
      float v = acc[i][j];
      if (mode == 1) v = tanhf(v + bias[col0 + tx * 4 + j]);
      vp[j] = v;
    }
    *(float4*)(Cb + (size_t)gr * ldbc + col0 + tx * 4) = vv;
  }
}

// ---------------------------------------------------------------------------
// el/er: per (b,m,n,h) dot of feat row segment with al/ar
// ---------------------------------------------------------------------------
__global__ __launch_bounds__(256) void elr_kernel(
    const float* __restrict__ feat, const float* __restrict__ al,
    const float* __restrict__ ar, float* __restrict__ el, float* __restrict__ er) {
  int b = blockIdx.z, m = blockIdx.y;
  int n0 = blockIdx.x * 64;
  int tid = threadIdx.x, lane = tid & 63, h = tid >> 6;
  float alv = al[m * HD + tid];
  float arv = ar[m * HD + tid];
  size_t bmN = (size_t)(b * M_ + m) * N_;
  const float* fb = feat + bmN * HD;
  for (int i = 0; i < 64; ++i) {
    int n = n0 + i;
    if (n >= N_) break;
    float f = fb[(size_t)n * HD + tid];
    float vl = f * alv, vr = f * arv;
#pragma unroll
    for (int s = 32; s > 0; s >>= 1) {
      vl += __shfl_xor(vl, s, 64);
      vr += __shfl_xor(vr, s, 64);
    }
    if (lane == 0) {
      el[(bmN + n) * H_ + h] = vl;
      er[(bmN + n) * H_ + h] = vr;
    }
  }
}

// ---------------------------------------------------------------------------
// GAT aggregation per destination: compact active sources, softmax, weighted sum.
// Block = (d, m, b); 256 threads = HD channels (h = tid>>6).
// ---------------------------------------------------------------------------
__global__ __launch_bounds__(256) void gat_agg(
    const unsigned char* __restrict__ maskT, const float* __restrict__ feat,
    const float* __restrict__ el, const float* __restrict__ er,
    const float* __restrict__ gb, float* __restrict__ zout) {
  int d = blockIdx.x, m = blockIdx.y, b = blockIdx.z;
  int tid = threadIdx.x;
  int lane = tid & 63, wid = tid >> 6;
  __shared__ int slist[1024];
  __shared__ float plog[4096];
  __shared__ float4 red[256];
  __shared__ int wcnt[4];
  size_t bmN = (size_t)(b * M_ + m) * N_;
  const unsigned char* mrow = maskT + (bmN + d) * NPAD;
  int cnt = 0;
  for (int base = 0; base < NPAD; base += 256) {
    int s = base + tid;
    bool act = (mrow[s] != 0);
    unsigned long long bal = __ballot(act);
    if (lane == 0) wcnt[wid] = __popcll(bal);
    __syncthreads();
    int woff = 0;
#pragma unroll
    for (int w = 0; w < 4; ++w)
      if (w < wid) woff += wcnt[w];
    int tot = wcnt[0] + wcnt[1] + wcnt[2] + wcnt[3];
    if (act) {
      int pos = cnt + woff + (int)__popcll(bal & ((1ull << lane) - 1ull));
      slist[pos] = s;
    }
    cnt += tot;
    __syncthreads();
  }
  float bias = gb[m * HD + tid];
  size_t zoff = ((size_t)(b * N_ + d) * M_ + m) * HD + tid;
  if (cnt == 0) {  // no incoming edges (or invalid dest): rst=0 -> elu(bias)
    float v = bias;
    zout[zoff] = (v > 0.f) ? v : (__expf(v) - 1.f);
    return;
  }
  const float* elb = el + bmN * H_;
  const float* erd = er + (bmN + d) * H_;
  float er0 = erd[0], er1 = erd[1], er2 = erd[2], er3 = erd[3];
  // pass 1: logits + per-thread max
  float mx0 = -1e30f, mx1 = -1e30f, mx2 = -1e30f, mx3 = -1e30f;
  for (int i = tid; i < cnt; i += 256) {
    int s = slist[i];
    const float* ep = elb + (size_t)s * H_;
    float v0 = ep[0] + er0; v0 = (v0 > 0.f) ? v0 : 0.2f * v0;
    float v1 = ep[1] + er1; v1 = (v1 > 0.f) ? v1 : 0.2f * v1;
    float v2 = ep[2] + er2; v2 = (v2 > 0.f) ? v2 : 0.2f * v2;
    float v3 = ep[3] + er3; v3 = (v3 > 0.f) ? v3 : 0.2f * v3;
    plog[i * 4 + 0] = v0; plog[i * 4 + 1] = v1;
    plog[i * 4 + 2] = v2; plog[i * 4 + 3] = v3;
    mx0 = fmaxf(mx0, v0); mx1 = fmaxf(mx1, v1);
    mx2 = fmaxf(mx2, v2); mx3 = fmaxf(mx3, v3);
  }
  red[tid] = make_float4(mx0, mx1, mx2, mx3);
  __syncthreads();
  for (int st = 128; st > 0; st >>= 1) {
    if (tid < st) {
      float4 a = red[tid], c = red[tid + st];
      red[tid] = make_float4(fmaxf(a.x, c.x), fmaxf(a.y, c.y), fmaxf(a.z, c.z), fmaxf(a.w, c.w));
    }
    __syncthreads();
  }
  float4 mx = red[0];
  // pass 2: exp + per-thread sum
  float s0 = 0.f, s1 = 0.f, s2 = 0.f, s3 = 0.f;
  for (int i = tid; i < cnt; i += 256) {
    float e0 = __expf(plog[i * 4 + 0] - mx.x); plog[i * 4 + 0] = e0; s0 += e0;
    float e1 = __expf(plog[i * 4 + 1] - mx.y); plog[i * 4 + 1] = e1; s1 += e1;
    float e2 = __expf(plog[i * 4 + 2] - mx.z); plog[i * 4 + 2] = e2; s2 += e2;
    float e3 = __expf(plog[i * 4 + 3] - mx.w); plog[i * 4 + 3] = e3; s3 += e3;
  }
  __syncthreads();  // everyone has read red[0]; safe to reuse
  red[tid] = make_float4(s0, s1, s2, s3);
  __syncthreads();
  for (int st = 128; st > 0; st >>= 1) {
    if (tid < st) {
      float4 a = red[tid], c = red[tid + st];
      red[tid] = make_float4(a.x + c.x, a.y + c.y, a.z + c.z, a.w + c.w);
    }
    __syncthreads();
  }
  float4 sm = red[0];
  float den = (wid == 0) ? sm.x : (wid == 1) ? sm.y : (wid == 2) ? sm.z : sm.w;
  float inv = 1.f / den;
  // pass 3: weighted feature accumulation (one channel per thread)
  const float* fb = feat + bmN * HD;
  float acc = 0.f;
  for (int i = 0; i < cnt; ++i) {
    int s = slist[i];
    float pw = plog[i * 4 + wid];
    acc += pw * fb[(size_t)s * HD + tid];
  }
  float v = acc * inv + bias;
  zout[zoff] = (v > 0.f) ? v : (__expf(v) - 1.f);
}

// ---------------------------------------------------------------------------
// p[row] = t[row,:] . W2   (one wave per row)
// ---------------------------------------------------------------------------
__global__ __launch_bounds__(256) void sem_p(const float* __restrict__ t,
                                             const float* __restrict__ W2,
                                             float* __restrict__ p, int Rows) {
  int row = blockIdx.x * 4 + (threadIdx.x >> 6);
  int lane = threadIdx.x & 63;
  if (row >= Rows) return;
  const float* tr = t + (size_t)row * SH;
  float v = tr[lane] * W2[lane] + tr[64 + lane] * W2[64 + lane];
#pragma unroll
  for (int s = 32; s > 0; s >>= 1) v += __shfl_xor(v, s, 64);
  if (lane == 0) p[row] = v;
}

// ---------------------------------------------------------------------------
// beta = softmax_m( sum_{b,n valid} p[b,n,m] / sum(node_nums) )  — 1 block
// ---------------------------------------------------------------------------
__global__ __launch_bounds__(256) void sem_beta(const float* __restrict__ p,
                                                const int* __restrict__ node_nums,
                                                float* __restrict__ beta) {
  __shared__ float red[256][M_];
  int tid = threadIdx.x;
  float loc[M_] = {};
  int nn0 = node_nums[0], nn1 = node_nums[1], nn2 = node_nums[2], nn3 = node_nums[3];
  for (int r = tid; r < B_ * N_ * M_; r += 256) {
    int m = r % M_;
    int bn = r / M_;
    int b = bn / N_, n = bn % N_;
    int nn = (b == 0) ? nn0 : (b == 1) ? nn1 : (b == 2) ? nn2 : nn3;
    if (n < nn) loc[m] += p[r];
  }
  for (int m = 0; m < M_; ++m) red[tid][m] = loc[m];
  __syncthreads();
  for (int st = 128; st > 0; st >>= 1) {
    if (tid < st)
      for (int m = 0; m < M_; ++m) red[tid][m] += red[tid + st][m];
    __syncthreads();
  }
  if (tid == 0) {
    float tot = (float)(nn0 + nn1 + nn2 + nn3);
    float w[M_], mx = -1e30f;
    for (int m = 0; m < M_; ++m) {
      w[m] = red[0][m] / tot;
      mx = fmaxf(mx, w[m]);
    }
    float s = 0.f;
    for (int m = 0; m < M_; ++m) {
      w[m] = __expf(w[m] - mx);
      s += w[m];
    }
    for (int m = 0; m < M_; ++m) beta[m] = w[m] / s;
  }
}

// ---------------------------------------------------------------------------
// h[b,n,hd] = sum_m beta[m] * z[b,n,m,hd]
// ---------------------------------------------------------------------------
__global__ __launch_bounds__(256) void sem_combine(const float* __restrict__ zb,
                                                   const float* __restrict__ beta,
                                                   float* __restrict__ hout) {
  int idx = blockIdx.x * 256 + threadIdx.x;
  int hd = idx & (HD - 1);
  int bn = idx >> 8;
  const float* zr = zb + (size_t)bn * M_ * HD + hd;
  float v = beta[0] * zr[0] + beta[1] * zr[HD] + beta[2] * zr[2 * HD] +
            beta[3] * zr[3 * HD] + beta[4] * zr[4 * HD];
  hout[idx] = v;
}

// ---------------------------------------------------------------------------
// logits = (h @ pred_W + pred_b) * nmask   (one wave per row)
// ---------------------------------------------------------------------------
__global__ __launch_bounds__(256) void pred_kernel(
    const float* __restrict__ h, const float* __restrict__ W,
    const float* __restrict__ bias, const int* __restrict__ node_nums,
    float* __restrict__ out) {
  int row = blockIdx.x * 4 + (threadIdx.x >> 6);
  int lane = threadIdx.x & 63;
  if (row >= B_ * N_) return;
  int b = row / N_, n = row % N_;
  const float* hr = h + (size_t)row * HD;
  float4 hv = *(const float4*)(hr + lane * 4);
  float res[OUTD];
#pragma unroll
  for (int o = 0; o < OUTD; ++o) {
    int k = lane * 4;
    float v = hv.x * W[(k + 0) * OUTD + o] + hv.y * W[(k + 1) * OUTD + o] +
              hv.z * W[(k + 2) * OUTD + o] + hv.w * W[(k + 3) * OUTD + o];
#pragma unroll
    for (int s = 32; s > 0; s >>= 1) v += __shfl_xor(v, s, 64);
    res[o] = v;
  }
  if (lane == 0) {
    float nm = (n < node_nums[b]) ? 1.f : 0.f;
#pragma unroll
    for (int o = 0; o < OUTD; ++o)
      out[(size_t)row * OUTD + o] = (res[o] + bias[o]) * nm;
  }
}

extern "C" void kernel_launch(void* const* d_in, const int* in_sizes, int n_in,
                              void* d_out, int out_size, void* d_ws, size_t ws_size,
                              hipStream_t stream) {
  const float* x = (const float*)d_in[0];
  const float* adj = (const float*)d_in[1];
  const int* node_nums = (const int*)d_in[2];
  const float* fc1 = (const float*)d_in[3];
  const float* al1 = (const float*)d_in[4];
  const float* ar1 = (const float*)d_in[5];
  const float* gb1 = (const float*)d_in[6];
  const float* sW1_1 = (const float*)d_in[7];
  const float* sb1_1 = (const float*)d_in[8];
  const float* sW2_1 = (const float*)d_in[9];
  const float* fc2 = (const float*)d_in[10];
  const float* al2 = (const float*)d_in[11];
  const float* ar2 = (const float*)d_in[12];
  const float* gb2 = (const float*)d_in[13];
  const float* sW1_2 = (const float*)d_in[14];
  const float* sb1_2 = (const float*)d_in[15];
  const float* sW2_2 = (const float*)d_in[16];
  const float* predW = (const float*)d_in[17];
  const float* predb = (const float*)d_in[18];
  float* out = (float*)d_out;

  char* ws = (char*)d_ws;
  size_t off = 0;
  unsigned char* maskT = (unsigned char*)(ws + off); off += (size_t)B_ * M_ * N_ * NPAD;
  float* feat = (float*)(ws + off); off += (size_t)B_ * M_ * N_ * HD * 4;
  float* el = (float*)(ws + off); off += (size_t)B_ * M_ * N_ * H_ * 4;
  float* er = (float*)(ws + off); off += (size_t)B_ * M_ * N_ * H_ * 4;
  float* zb = (float*)(ws + off); off += (size_t)B_ * N_ * M_ * HD * 4;
  float* t = (float*)(ws + off); off += (size_t)B_ * N_ * M_ * SH * 4;
  float* p = (float*)(ws + off); off += (size_t)B_ * N_ * M_ * 4;
  float* h1 = (float*)(ws + off); off += (size_t)B_ * N_ * HD * 4;
  float* beta = (float*)(ws + off); off += 256;

  const int ROWS = B_ * N_ * M_;  // 20000

  build_maskT<<<dim3(16, 16, B_ * M_), 256, 0, stream>>>(adj, node_nums, maskT);

  // ---- layer 1 ----
  gemm64<<<dim3(16, HD / 64, B_ * M_), 256, 0, stream>>>(
      x, FIN, M_, (size_t)M_ * N_ * FIN, fc1, (size_t)FIN * HD,
      feat, (size_t)N_ * HD, N_, FIN, HD, 0, nullptr);
  elr_kernel<<<dim3(16, M_, B_), 256, 0, stream>>>(feat, al1, ar1, el, er);
  gat_agg<<<dim3(N_, M_, B_), 256, 0, stream>>>(maskT, feat, el, er, gb1, zb);
  gemm64<<<dim3((ROWS + 63) / 64, SH / 64, 1), 256, 0, stream>>>(
      zb, HD, 1, 0, sW1_1, 0, t, 0, ROWS, HD, SH, 1, sb1_1);
  sem_p<<<dim3(ROWS / 4), 256, 0, stream>>>(t, sW2_1, p, ROWS);
  sem_beta<<<dim3(1), 256, 0, stream>>>(p, node_nums, beta);
  sem_combine<<<dim3(B_ * N_ * HD / 256), 256, 0, stream>>>(zb, beta, h1);

  // ---- layer 2 ----
  gemm64<<<dim3(16, HD / 64, B_ * M_), 256, 0, stream>>>(
      h1, HD, M_, (size_t)N_ * HD, fc2, (size_t)HD * HD,
      feat, (size_t)N_ * HD, N_, HD, HD, 0, nullptr);
  elr_kernel<<<dim3(16, M_, B_), 256, 0, stream>>>(feat, al2, ar2, el, er);
  gat_agg<<<dim3(N_, M_, B_), 256, 0, stream>>>(maskT, feat, el, er, gb2, zb);
  gemm64<<<dim3((ROWS + 63) / 64, SH / 64, 1), 256, 0, stream>>>(
      zb, HD, 1, 0, sW1_2, 0, t, 0, ROWS, HD, SH, 1, sb1_2);
  sem_p<<<dim3(ROWS / 4), 256, 0, stream>>>(t, sW2_2, p, ROWS);
  sem_beta<<<dim3(1), 256, 0, stream>>>(p, node_nums, beta);
  sem_combine<<<dim3(B_ * N_ * HD / 256), 256, 0, stream>>>(zb, beta, h1);

  // ---- prediction head ----
  pred_kernel<<<dim3(B_ * N_ / 4), 256, 0, stream>>>(h1, predW, predb, node_nums, out);
}

// Round 2
// 346.018 us; speedup vs baseline: 1.2402x; 1.2402x over previous
//
#include <hip/hip_runtime.h>

#define B_ 4
#define M_ 5
#define N_ 1000
#define FIN 64
#define H_ 4
#define D_ 64
#define HD 256
#define SH 128
#define OUTD 5
#define NPAD 1024
#define NW 16  // u64 words per dest row (NPAD/64)
#define THRESH_ 0.97f

// ---------------------------------------------------------------------------
// Build bit-packed transposed edge mask:
// maskW[(bm*N + d)*16 + w] bit l  =  edge (s = w*64+l) -> d, masked by nn.
// 64x64 adj tiles through LDS (coalesced read), ballot to pack bits.
// ---------------------------------------------------------------------------
__global__ __launch_bounds__(256) void build_maskbits(
    const float* __restrict__ adj, const int* __restrict__ node_nums,
    unsigned long long* __restrict__ maskW) {
  int bm = blockIdx.z;
  int b = bm / M_;
  int s0 = blockIdx.x * 64, d0 = blockIdx.y * 64;
  int nn = node_nums[b];
  __shared__ unsigned char tile[64][65];
  const float* arow = adj + (size_t)bm * N_ * N_;
  int tid = threadIdx.x;
#pragma unroll
  for (int k = 0; k < 16; ++k) {
    int idx = k * 256 + tid;
    int sl = idx >> 6, dl = idx & 63;
    int s = s0 + sl, d = d0 + dl;
    unsigned char v = 0;
    if (s < nn && d < nn && s < N_ && d < N_)
      v = (arow[(size_t)s * N_ + d] > THRESH_) ? 1 : 0;
    tile[sl][dl] = v;
  }
  __syncthreads();
  int w = tid >> 6, lane = tid & 63;
#pragma unroll
  for (int j = 0; j < 16; ++j) {
    int dl = w * 16 + j;
    bool act = tile[lane][dl] != 0;
    unsigned long long word = __ballot(act);
    int d = d0 + dl;
    if (lane == 0 && d < N_)
      maskW[((size_t)bm * N_ + d) * NW + blockIdx.x] = word;
  }
}

// ---------------------------------------------------------------------------
// Generic fp32 tiled GEMM: C[z] = A[z] @ B[z]  (64x64 tile, 4x4 microtile)
// mode 1: C = tanh(C + bias[col])
// ---------------------------------------------------------------------------
__global__ __launch_bounds__(256) void gemm64(
    const float* __restrict__ A, int lda, int Mz, size_t aZstride,
    const float* __restrict__ Bw, size_t bZstride,
    float* __restrict__ C, size_t cZstride,
    int Mrows, int K, int ldbc, int mode, const float* __restrict__ bias) {
  __shared__ float As[16][64];
  __shared__ float Bs[16][64];
  int z = blockIdx.z;
  const float* Ab = A + (size_t)(z / Mz) * aZstride;
  const float* Bb = Bw + (size_t)(z % Mz) * bZstride;
  float* Cb = C + (size_t)z * cZstride;
  int row0 = blockIdx.x * 64, col0 = blockIdx.y * 64;
  int tid = threadIdx.x;
  int tx = tid & 15, ty = tid >> 4;
  float acc[4][4] = {};
  int am = tid >> 2, akq = (tid & 3) * 4;
  int bk = tid >> 4, bnq = (tid & 15) * 4;
  for (int k0 = 0; k0 < K; k0 += 16) {
    float4 av;
    int gr = row0 + am;
    if (gr < Mrows)
      av = *(const float4*)(Ab + (size_t)gr * lda + k0 + akq);
    else
      av = make_float4(0.f, 0.f, 0.f, 0.f);
    As[akq + 0][am] = av.x;
    As[akq + 1][am] = av.y;
    As[akq + 2][am] = av.z;
    As[akq + 3][am] = av.w;
    float4 bv = *(const float4*)(Bb + (size_t)(k0 + bk) * ldbc + col0 + bnq);
    *(float4*)&Bs[bk][bnq] = bv;
    __syncthreads();
#pragma unroll
    for (int kk = 0; kk < 16; ++kk) {
      float a0[4], b0[4];
      *(float4*)a0 = *(const float4*)&As[kk][ty * 4];
      *(float4*)b0 = *(const float4*)&Bs[kk][tx * 4];
#pragma unroll
      for (int i = 0; i < 4; ++i)
#pragma unroll
        for (int j = 0; j < 4; ++j) acc[i][j] += a0[i] * b0[j];
    }
    __syncthreads();
  }
#pragma unroll
  for (int i = 0; i < 4; ++i) {
    int gr = row0 + ty * 4 + i;
    if (gr >= Mrows) continue;
    float4 vv;
    float* vp = (float*)&vv;
#pragma unroll
    for (int j = 0; j < 4; ++j) {
      float v = acc[i][j];
      if (mode == 1) v = tanhf(v + bias[col0 + tx * 4 + j]);
      vp[j] = v;
    }
    *(float4*)(Cb + (size_t)gr * ldbc + col0 + tx * 4) = vv;
  }
}

// ---------------------------------------------------------------------------
// el/er: per (b,m,n,h) dot of feat row segment with al/ar
// ---------------------------------------------------------------------------
__global__ __launch_bounds__(256) void elr_kernel(
    const float* __restrict__ feat, const float* __restrict__ al,
    const float* __restrict__ ar, float* __restrict__ el, float* __restrict__ er) {
  int b = blockIdx.z, m = blockIdx.y;
  int n0 = blockIdx.x * 64;
  int tid = threadIdx.x, lane = tid & 63, h = tid >> 6;
  float alv = al[m * HD + tid];
  float arv = ar[m * HD + tid];
  size_t bmN = (size_t)(b * M_ + m) * N_;
  const float* fb = feat + bmN * HD;
  for (int i = 0; i < 64; ++i) {
    int n = n0 + i;
    if (n >= N_) break;
    float f = fb[(size_t)n * HD + tid];
    float vl = f * alv, vr = f * arv;
#pragma unroll
    for (int s = 32; s > 0; s >>= 1) {
      vl += __shfl_xor(vl, s, 64);
      vr += __shfl_xor(vr, s, 64);
    }
    if (lane == 0) {
      el[(bmN + n) * H_ + h] = vl;
      er[(bmN + n) * H_ + h] = vr;
    }
  }
}

// ---------------------------------------------------------------------------
// GAT aggregation: ONE WAVE per destination (b,m,d). No __syncthreads.
// Lane owns 4 channels of one head (h = lane>>4); per-head softmax state is
// redundantly identical across the 16 lanes of a head -> no cross-lane ops.
// Online (rescaling) softmax merges exp + weighted-sum into one pass.
// ---------------------------------------------------------------------------
__global__ __launch_bounds__(256) void gat_agg(
    const unsigned long long* __restrict__ maskW, const float* __restrict__ feat,
    const float* __restrict__ el, const float* __restrict__ er,
    const float* __restrict__ gb, float* __restrict__ zout) {
  int wid = threadIdx.x >> 6, lane = threadIdx.x & 63;
  int gw = blockIdx.x * 4 + wid;  // dest index over (b,m,d); grid exact
  int d = gw % N_, bm = gw / N_;
  int m = bm % M_, b = bm / M_;
  __shared__ int slist_all[4][1024];
  int* slist = slist_all[wid];

  // --- compact active sources (wave-synchronous, barrier-free) ---
  const unsigned long long* mrow = maskW + ((size_t)bm * N_ + d) * NW;
  int cnt = 0;
#pragma unroll
  for (int w16 = 0; w16 < NW; ++w16) {
    unsigned long long word = mrow[w16];
    if (word) {
      if ((word >> lane) & 1ull) {
        int pos = cnt + (int)__popcll(word & ((1ull << lane) - 1ull));
        slist[pos] = w16 * 64 + lane;
      }
      cnt += (int)__popcll(word);
    }
  }

  int h = lane >> 4;
  float4 bias = *(const float4*)(gb + m * HD + lane * 4);
  size_t zoff = ((size_t)(b * N_ + d) * M_ + m) * HD + lane * 4;
  if (cnt == 0) {  // no incoming edges: rst = 0 -> elu(bias)
    float4 o;
    o.x = bias.x > 0.f ? bias.x : (__expf(bias.x) - 1.f);
    o.y = bias.y > 0.f ? bias.y : (__expf(bias.y) - 1.f);
    o.z = bias.z > 0.f ? bias.z : (__expf(bias.z) - 1.f);
    o.w = bias.w > 0.f ? bias.w : (__expf(bias.w) - 1.f);
    *(float4*)(zout + zoff) = o;
    return;
  }

  size_t bmN = (size_t)bm * N_;
  float erv = er[(bmN + d) * H_ + h];
  const float* elb = el + bmN * H_;
  const float* fb = feat + bmN * HD;

  float mx = -1e30f, den = 0.f;
  float ax = 0.f, ay = 0.f, az = 0.f, aw = 0.f;
  for (int i = 0; i < cnt; ++i) {
    int s = slist[i];
    float v = elb[(size_t)s * H_ + h] + erv;
    v = v > 0.f ? v : 0.2f * v;  // leaky_relu
    float4 f = *(const float4*)(fb + (size_t)s * HD + lane * 4);
    float nm = fmaxf(mx, v);
    float r = __expf(mx - nm);   // ==1 when no new max
    float w = __expf(v - nm);
    den = den * r + w;
    ax = ax * r + w * f.x;
    ay = ay * r + w * f.y;
    az = az * r + w * f.z;
    aw = aw * r + w * f.w;
    mx = nm;
  }
  float inv = 1.f / den;
  float4 o;
  float vx = ax * inv + bias.x;
  float vy = ay * inv + bias.y;
  float vz = az * inv + bias.z;
  float vw = aw * inv + bias.w;
  o.x = vx > 0.f ? vx : (__expf(vx) - 1.f);
  o.y = vy > 0.f ? vy : (__expf(vy) - 1.f);
  o.z = vz > 0.f ? vz : (__expf(vz) - 1.f);
  o.w = vw > 0.f ? vw : (__expf(vw) - 1.f);
  *(float4*)(zout + zoff) = o;
}

// ---------------------------------------------------------------------------
// p[row] = t[row,:] . W2   (one wave per row)
// ---------------------------------------------------------------------------
__global__ __launch_bounds__(256) void sem_p(const float* __restrict__ t,
                                             const float* __restrict__ W2,
                                             float* __restrict__ p, int Rows) {
  int row = blockIdx.x * 4 + (threadIdx.x >> 6);
  int lane = threadIdx.x & 63;
  if (row >= Rows) return;
  const float* tr = t + (size_t)row * SH;
  float v = tr[lane] * W2[lane] + tr[64 + lane] * W2[64 + lane];
#pragma unroll
  for (int s = 32; s > 0; s >>= 1) v += __shfl_xor(v, s, 64);
  if (lane == 0) p[row] = v;
}

// ---------------------------------------------------------------------------
// beta = softmax_m( sum_{b,n valid} p[b,n,m] / sum(node_nums) )  — 1 block
// ---------------------------------------------------------------------------
__global__ __launch_bounds__(256) void sem_beta(const float* __restrict__ p,
                                                const int* __restrict__ node_nums,
                                                float* __restrict__ beta) {
  __shared__ float red[256][M_];
  int tid = threadIdx.x;
  float loc[M_] = {};
  int nn0 = node_nums[0], nn1 = node_nums[1], nn2 = node_nums[2], nn3 = node_nums[3];
  for (int r = tid; r < B_ * N_ * M_; r += 256) {
    int m = r % M_;
    int bn = r / M_;
    int b = bn / N_, n = bn % N_;
    int nn = (b == 0) ? nn0 : (b == 1) ? nn1 : (b == 2) ? nn2 : nn3;
    if (n < nn) loc[m] += p[r];
  }
  for (int m = 0; m < M_; ++m) red[tid][m] = loc[m];
  __syncthreads();
  for (int st = 128; st > 0; st >>= 1) {
    if (tid < st)
      for (int m = 0; m < M_; ++m) red[tid][m] += red[tid + st][m];
    __syncthreads();
  }
  if (tid == 0) {
    float tot = (float)(nn0 + nn1 + nn2 + nn3);
    float w[M_], mx = -1e30f;
    for (int m = 0; m < M_; ++m) {
      w[m] = red[0][m] / tot;
      mx = fmaxf(mx, w[m]);
    }
    float s = 0.f;
    for (int m = 0; m < M_; ++m) {
      w[m] = __expf(w[m] - mx);
      s += w[m];
    }
    for (int m = 0; m < M_; ++m) beta[m] = w[m] / s;
  }
}

// ---------------------------------------------------------------------------
// h[b,n,hd] = sum_m beta[m] * z[b,n,m,hd]
// ---------------------------------------------------------------------------
__global__ __launch_bounds__(256) void sem_combine(const float* __restrict__ zb,
                                                   const float* __restrict__ beta,
                                                   float* __restrict__ hout) {
  int idx = blockIdx.x * 256 + threadIdx.x;
  int hd = idx & (HD - 1);
  int bn = idx >> 8;
  const float* zr = zb + (size_t)bn * M_ * HD + hd;
  float v = beta[0] * zr[0] + beta[1] * zr[HD] + beta[2] * zr[2 * HD] +
            beta[3] * zr[3 * HD] + beta[4] * zr[4 * HD];
  hout[idx] = v;
}

// ---------------------------------------------------------------------------
// logits = (h @ pred_W + pred_b) * nmask   (one wave per row)
// ---------------------------------------------------------------------------
__global__ __launch_bounds__(256) void pred_kernel(
    const float* __restrict__ h, const float* __restrict__ W,
    const float* __restrict__ bias, const int* __restrict__ node_nums,
    float* __restrict__ out) {
  int row = blockIdx.x * 4 + (threadIdx.x >> 6);
  int lane = threadIdx.x & 63;
  if (row >= B_ * N_) return;
  int b = row / N_, n = row % N_;
  const float* hr = h + (size_t)row * HD;
  float4 hv = *(const float4*)(hr + lane * 4);
  float res[OUTD];
#pragma unroll
  for (int o = 0; o < OUTD; ++o) {
    int k = lane * 4;
    float v = hv.x * W[(k + 0) * OUTD + o] + hv.y * W[(k + 1) * OUTD + o] +
              hv.z * W[(k + 2) * OUTD + o] + hv.w * W[(k + 3) * OUTD + o];
#pragma unroll
    for (int s = 32; s > 0; s >>= 1) v += __shfl_xor(v, s, 64);
    res[o] = v;
  }
  if (lane == 0) {
    float nm = (n < node_nums[b]) ? 1.f : 0.f;
#pragma unroll
    for (int o = 0; o < OUTD; ++o)
      out[(size_t)row * OUTD + o] = (res[o] + bias[o]) * nm;
  }
}

extern "C" void kernel_launch(void* const* d_in, const int* in_sizes, int n_in,
                              void* d_out, int out_size, void* d_ws, size_t ws_size,
                              hipStream_t stream) {
  const float* x = (const float*)d_in[0];
  const float* adj = (const float*)d_in[1];
  const int* node_nums = (const int*)d_in[2];
  const float* fc1 = (const float*)d_in[3];
  const float* al1 = (const float*)d_in[4];
  const float* ar1 = (const float*)d_in[5];
  const float* gb1 = (const float*)d_in[6];
  const float* sW1_1 = (const float*)d_in[7];
  const float* sb1_1 = (const float*)d_in[8];
  const float* sW2_1 = (const float*)d_in[9];
  const float* fc2 = (const float*)d_in[10];
  const float* al2 = (const float*)d_in[11];
  const float* ar2 = (const float*)d_in[12];
  const float* gb2 = (const float*)d_in[13];
  const float* sW1_2 = (const float*)d_in[14];
  const float* sb1_2 = (const float*)d_in[15];
  const float* sW2_2 = (const float*)d_in[16];
  const float* predW = (const float*)d_in[17];
  const float* predb = (const float*)d_in[18];
  float* out = (float*)d_out;

  char* ws = (char*)d_ws;
  size_t off = 0;
  unsigned long long* maskW = (unsigned long long*)(ws + off);
  off += (size_t)B_ * M_ * N_ * NW * 8;
  float* feat = (float*)(ws + off); off += (size_t)B_ * M_ * N_ * HD * 4;
  float* el = (float*)(ws + off); off += (size_t)B_ * M_ * N_ * H_ * 4;
  float* er = (float*)(ws + off); off += (size_t)B_ * M_ * N_ * H_ * 4;
  float* zb = (float*)(ws + off); off += (size_t)B_ * N_ * M_ * HD * 4;
  float* t = (float*)(ws + off); off += (size_t)B_ * N_ * M_ * SH * 4;
  float* p = (float*)(ws + off); off += (size_t)B_ * N_ * M_ * 4;
  float* h1 = (float*)(ws + off); off += (size_t)B_ * N_ * HD * 4;
  float* beta = (float*)(ws + off); off += 256;

  const int ROWS = B_ * N_ * M_;  // 20000

  build_maskbits<<<dim3(16, 16, B_ * M_), 256, 0, stream>>>(adj, node_nums, maskW);

  // ---- layer 1 ----
  gemm64<<<dim3(16, HD / 64, B_ * M_), 256, 0, stream>>>(
      x, FIN, M_, (size_t)M_ * N_ * FIN, fc1, (size_t)FIN * HD,
      feat, (size_t)N_ * HD, N_, FIN, HD, 0, nullptr);
  elr_kernel<<<dim3(16, M_, B_), 256, 0, stream>>>(feat, al1, ar1, el, er);
  gat_agg<<<dim3(ROWS / 4), 256, 0, stream>>>(maskW, feat, el, er, gb1, zb);
  gemm64<<<dim3((ROWS + 63) / 64, SH / 64, 1), 256, 0, stream>>>(
      zb, HD, 1, 0, sW1_1, 0, t, 0, ROWS, HD, SH, 1, sb1_1);
  sem_p<<<dim3(ROWS / 4), 256, 0, stream>>>(t, sW2_1, p, ROWS);
  sem_beta<<<dim3(1), 256, 0, stream>>>(p, node_nums, beta);
  sem_combine<<<dim3(B_ * N_ * HD / 256), 256, 0, stream>>>(zb, beta, h1);

  // ---- layer 2 ----
  gemm64<<<dim3(16, HD / 64, B_ * M_), 256, 0, stream>>>(
      h1, HD, M_, (size_t)N_ * HD, fc2, (size_t)HD * HD,
      feat, (size_t)N_ * HD, N_, HD, HD, 0, nullptr);
  elr_kernel<<<dim3(16, M_, B_), 256, 0, stream>>>(feat, al2, ar2, el, er);
  gat_agg<<<dim3(ROWS / 4), 256, 0, stream>>>(maskW, feat, el, er, gb2, zb);
  gemm64<<<dim3((ROWS + 63) / 64, SH / 64, 1), 256, 0, stream>>>(
      zb, HD, 1, 0, sW1_2, 0, t, 0, ROWS, HD, SH, 1, sb1_2);
  sem_p<<<dim3(ROWS / 4), 256, 0, stream>>>(t, sW2_2, p, ROWS);
  sem_beta<<<dim3(1), 256, 0, stream>>>(p, node_nums, beta);
  sem_combine<<<dim3(B_ * N_ * HD / 256), 256, 0, stream>>>(zb, beta, h1);

  // ---- prediction head ----
  pred_kernel<<<dim3(B_ * N_ / 4), 256, 0, stream>>>(h1, predW, predb, node_nums, out);
}

// Round 3
// 320.139 us; speedup vs baseline: 1.3405x; 1.0808x over previous
//
#include <hip/hip_runtime.h>
#include <hip/hip_bf16.h>

#define B_ 4
#define M_ 5
#define N_ 1000
#define FIN 64
#define H_ 4
#define D_ 64
#define HD 256
#define SH 128
#define OUTD 5
#define NW 16  // u64 words per dest row (1024/64)
#define THRESH_ 0.97f

typedef unsigned short u16;
typedef u16 us8 __attribute__((ext_vector_type(8)));
typedef short s16x8 __attribute__((ext_vector_type(8)));
typedef float f32x4 __attribute__((ext_vector_type(4)));

__device__ inline u16 bf16_bits(float v) {
  __hip_bfloat16 h = __float2bfloat16(v);
  return *reinterpret_cast<u16*>(&h);
}
__device__ inline float bf16_val(u16 b) {
  __hip_bfloat16 h;
  *reinterpret_cast<u16*>(&h) = b;
  return __bfloat162float(h);
}
__device__ inline void split2(float v, u16& h, u16& l) {
  h = bf16_bits(v);
  l = bf16_bits(v - bf16_val(h));
}

// ---------------------------------------------------------------------------
// Build bit-packed transposed edge mask (shared by both layers).
// ---------------------------------------------------------------------------
__global__ __launch_bounds__(256) void build_maskbits(
    const float* __restrict__ adj, const int* __restrict__ node_nums,
    unsigned long long* __restrict__ maskW) {
  int bm = blockIdx.z;
  int b = bm / M_;
  int s0 = blockIdx.x * 64, d0 = blockIdx.y * 64;
  int nn = node_nums[b];
  __shared__ unsigned char tile[64][65];
  const float* arow = adj + (size_t)bm * N_ * N_;
  int tid = threadIdx.x;
#pragma unroll
  for (int k = 0; k < 16; ++k) {
    int idx = k * 256 + tid;
    int sl = idx >> 6, dl = idx & 63;
    int s = s0 + sl, d = d0 + dl;
    unsigned char v = 0;
    if (s < nn && d < nn && s < N_ && d < N_)
      v = (arow[(size_t)s * N_ + d] > THRESH_) ? 1 : 0;
    tile[sl][dl] = v;
  }
  __syncthreads();
  int w = tid >> 6, lane = tid & 63;
#pragma unroll
  for (int j = 0; j < 16; ++j) {
    int dl = w * 16 + j;
    bool act = tile[lane][dl] != 0;
    unsigned long long word = __ballot(act);
    int d = d0 + dl;
    if (lane == 0 && d < N_)
      maskW[((size_t)bm * N_ + d) * NW + blockIdx.x] = word;
  }
}

// ---------------------------------------------------------------------------
// Elementwise split fp32 -> bf16 hi + lo (z-batched, float4 vectorized).
// ---------------------------------------------------------------------------
__global__ __launch_bounds__(256) void split_kernel(
    const float* __restrict__ src, size_t sZ,
    u16* __restrict__ hi, u16* __restrict__ lo, size_t dZ, int n4) {
  int z = blockIdx.z;
  int i = blockIdx.x * 256 + threadIdx.x;
  if (i >= n4) return;
  const float4* s = (const float4*)(src + z * sZ);
  float4 v = s[i];
  ushort4 h, l;
  split2(v.x, h.x, l.x);
  split2(v.y, h.y, l.y);
  split2(v.z, h.z, l.z);
  split2(v.w, h.w, l.w);
  *(ushort4*)(hi + z * dZ + (size_t)i * 4) = h;
  *(ushort4*)(lo + z * dZ + (size_t)i * 4) = l;
}

// ---------------------------------------------------------------------------
// Transpose + split: src (K x N) fp32  ->  dst (N x K) bf16 hi/lo (z-batched).
// ---------------------------------------------------------------------------
__global__ __launch_bounds__(256) void splitT_kernel(
    const float* __restrict__ src, size_t sZ,
    u16* __restrict__ hiT, u16* __restrict__ loT, size_t dZ, int K, int N) {
  int z = blockIdx.z;
  const float* s = src + z * sZ;
  int k0 = blockIdx.x * 32, n0 = blockIdx.y * 32;
  __shared__ float tile[32][33];
  int tid = threadIdx.x;
  int kl = tid >> 3, nq = (tid & 7) * 4;
  *(float4*)&tile[kl][nq] = *(const float4*)(s + (size_t)(k0 + kl) * N + n0 + nq);
  __syncthreads();
  int nl = tid >> 3, kq = (tid & 7) * 4;
  ushort4 h, l;
  split2(tile[kq + 0][nl], h.x, l.x);
  split2(tile[kq + 1][nl], h.y, l.y);
  split2(tile[kq + 2][nl], h.z, l.z);
  split2(tile[kq + 3][nl], h.w, l.w);
  size_t o = z * dZ + (size_t)(n0 + nl) * K + k0 + kq;
  *(ushort4*)(hiT + o) = h;
  *(ushort4*)(loT + o) = l;
}

// ---------------------------------------------------------------------------
// Split-bf16 MFMA GEMM: C[z] = A[z] @ B[z] with A (Mrows x K) row-major hi/lo,
// B given TRANSPOSED (Nc x K) row-major hi/lo. 64x64 block tile, 4 waves,
// each wave 32x32 via 2x2 mfma_f32_16x16x32_bf16; 3 mfma per product
// (hh + hl + lh) gives fp32-grade accuracy. mode 1: C = tanh(C + bias[col]).
// ---------------------------------------------------------------------------
__global__ __launch_bounds__(256) void gemm_mfma(
    const u16* __restrict__ Ah, const u16* __restrict__ Al, int Mz, size_t aZ,
    const u16* __restrict__ Bh, const u16* __restrict__ Bl, size_t bZ,
    float* __restrict__ C, size_t cZ, int Mrows, int K, int Nc,
    int mode, const float* __restrict__ bias) {
  __shared__ u16 sAh[64][40], sAl[64][40], sBh[64][40], sBl[64][40];  // 80B rows
  int z = blockIdx.z;
  const u16* Ahb = Ah + (size_t)(z / Mz) * aZ;
  const u16* Alb = Al + (size_t)(z / Mz) * aZ;
  const u16* Bhb = Bh + (size_t)(z % Mz) * bZ;
  const u16* Blb = Bl + (size_t)(z % Mz) * bZ;
  float* Cb = C + (size_t)z * cZ;
  int row0 = blockIdx.x * 64, col0 = blockIdx.y * 64;
  int tid = threadIdx.x;
  int arow = tid >> 2, akq = (tid & 3) * 8;
  int wid = tid >> 6, lane = tid & 63;
  int wr = (wid >> 1) * 32, wc = (wid & 1) * 32;
  int lrow = lane & 15, kseg = (lane >> 4) * 8;
  f32x4 zero4 = {0.f, 0.f, 0.f, 0.f};
  f32x4 acc[2][2];
  acc[0][0] = zero4; acc[0][1] = zero4; acc[1][0] = zero4; acc[1][1] = zero4;
  for (int k0 = 0; k0 < K; k0 += 32) {
    us8 av = {0, 0, 0, 0, 0, 0, 0, 0}, alv = av;
    int gr = row0 + arow;
    if (gr < Mrows) {
      av = *(const us8*)(Ahb + (size_t)gr * K + k0 + akq);
      alv = *(const us8*)(Alb + (size_t)gr * K + k0 + akq);
    }
    *(us8*)&sAh[arow][akq] = av;
    *(us8*)&sAl[arow][akq] = alv;
    us8 bv = *(const us8*)(Bhb + (size_t)(col0 + arow) * K + k0 + akq);
    us8 blv = *(const us8*)(Blb + (size_t)(col0 + arow) * K + k0 + akq);
    *(us8*)&sBh[arow][akq] = bv;
    *(us8*)&sBl[arow][akq] = blv;
    __syncthreads();
    s16x8 aH[2], aL[2], bH[2], bL[2];
#pragma unroll
    for (int i = 0; i < 2; ++i) {
      aH[i] = *(const s16x8*)&sAh[wr + 16 * i + lrow][kseg];
      aL[i] = *(const s16x8*)&sAl[wr + 16 * i + lrow][kseg];
      bH[i] = *(const s16x8*)&sBh[wc + 16 * i + lrow][kseg];
      bL[i] = *(const s16x8*)&sBl[wc + 16 * i + lrow][kseg];
    }
#pragma unroll
    for (int i = 0; i < 2; ++i)
#pragma unroll
      for (int j = 0; j < 2; ++j) {
        acc[i][j] = __builtin_amdgcn_mfma_f32_16x16x32_bf16(aH[i], bH[j], acc[i][j], 0, 0, 0);
        acc[i][j] = __builtin_amdgcn_mfma_f32_16x16x32_bf16(aH[i], bL[j], acc[i][j], 0, 0, 0);
        acc[i][j] = __builtin_amdgcn_mfma_f32_16x16x32_bf16(aL[i], bH[j], acc[i][j], 0, 0, 0);
      }
    __syncthreads();
  }
#pragma unroll
  for (int i = 0; i < 2; ++i)
#pragma unroll
    for (int j = 0; j < 2; ++j) {
      int ccol = col0 + wc + 16 * j + lrow;
#pragma unroll
      for (int r = 0; r < 4; ++r) {
        int crow = row0 + wr + 16 * i + (lane >> 4) * 4 + r;
        if (crow < Mrows) {
          float v = acc[i][j][r];
          if (mode == 1) v = tanhf(v + bias[ccol]);
          Cb[(size_t)crow * Nc + ccol] = v;
        }
      }
    }
}

// ---------------------------------------------------------------------------
// el/er: per (b,m,n,h) dot of feat row segment with al/ar
// ---------------------------------------------------------------------------
__global__ __launch_bounds__(256) void elr_kernel(
    const float* __restrict__ feat, const float* __restrict__ al,
    const float* __restrict__ ar, float* __restrict__ el, float* __restrict__ er) {
  int b = blockIdx.z, m = blockIdx.y;
  int n0 = blockIdx.x * 64;
  int tid = threadIdx.x, lane = tid & 63, h = tid >> 6;
  float alv = al[m * HD + tid];
  float arv = ar[m * HD + tid];
  size_t bmN = (size_t)(b * M_ + m) * N_;
  const float* fb = feat + bmN * HD;
  for (int i = 0; i < 64; ++i) {
    int n = n0 + i;
    if (n >= N_) break;
    float f = fb[(size_t)n * HD + tid];
    float vl = f * alv, vr = f * arv;
#pragma unroll
    for (int s = 32; s > 0; s >>= 1) {
      vl += __shfl_xor(vl, s, 64);
      vr += __shfl_xor(vr, s, 64);
    }
    if (lane == 0) {
      el[(bmN + n) * H_ + h] = vl;
      er[(bmN + n) * H_ + h] = vr;
    }
  }
}

// ---------------------------------------------------------------------------
// GAT aggregation: one wave per destination, barrier-free, online softmax.
// ---------------------------------------------------------------------------
__global__ __launch_bounds__(256) void gat_agg(
    const unsigned long long* __restrict__ maskW, const float* __restrict__ feat,
    const float* __restrict__ el, const float* __restrict__ er,
    const float* __restrict__ gb, float* __restrict__ zout) {
  int wid = threadIdx.x >> 6, lane = threadIdx.x & 63;
  int gw = blockIdx.x * 4 + wid;
  int d = gw % N_, bm = gw / N_;
  int m = bm % M_, b = bm / M_;
  __shared__ int slist_all[4][1024];
  int* slist = slist_all[wid];

  const unsigned long long* mrow = maskW + ((size_t)bm * N_ + d) * NW;
  int cnt = 0;
#pragma unroll
  for (int w16 = 0; w16 < NW; ++w16) {
    unsigned long long word = mrow[w16];
    if (word) {
      if ((word >> lane) & 1ull) {
        int pos = cnt + (int)__popcll(word & ((1ull << lane) - 1ull));
        slist[pos] = w16 * 64 + lane;
      }
      cnt += (int)__popcll(word);
    }
  }

  int h = lane >> 4;
  float4 bias = *(const float4*)(gb + m * HD + lane * 4);
  size_t zoff = ((size_t)(b * N_ + d) * M_ + m) * HD + lane * 4;
  if (cnt == 0) {
    float4 o;
    o.x = bias.x > 0.f ? bias.x : (__expf(bias.x) - 1.f);
    o.y = bias.y > 0.f ? bias.y : (__expf(bias.y) - 1.f);
    o.z = bias.z > 0.f ? bias.z : (__expf(bias.z) - 1.f);
    o.w = bias.w > 0.f ? bias.w : (__expf(bias.w) - 1.f);
    *(float4*)(zout + zoff) = o;
    return;
  }

  size_t bmN = (size_t)bm * N_;
  float erv = er[(bmN + d) * H_ + h];
  const float* elb = el + bmN * H_;
  const float* fb = feat + bmN * HD;

  float mx = -1e30f, den = 0.f;
  float ax = 0.f, ay = 0.f, az = 0.f, aw = 0.f;
  for (int i = 0; i < cnt; ++i) {
    int s = slist[i];
    float v = elb[(size_t)s * H_ + h] + erv;
    v = v > 0.f ? v : 0.2f * v;
    float4 f = *(const float4*)(fb + (size_t)s * HD + lane * 4);
    float nm = fmaxf(mx, v);
    float r = __expf(mx - nm);
    float w = __expf(v - nm);
    den = den * r + w;
    ax = ax * r + w * f.x;
    ay = ay * r + w * f.y;
    az = az * r + w * f.z;
    aw = aw * r + w * f.w;
    mx = nm;
  }
  float inv = 1.f / den;
  float4 o;
  float vx = ax * inv + bias.x;
  float vy = ay * inv + bias.y;
  float vz = az * inv + bias.z;
  float vw = aw * inv + bias.w;
  o.x = vx > 0.f ? vx : (__expf(vx) - 1.f);
  o.y = vy > 0.f ? vy : (__expf(vy) - 1.f);
  o.z = vz > 0.f ? vz : (__expf(vz) - 1.f);
  o.w = vw > 0.f ? vw : (__expf(vw) - 1.f);
  *(float4*)(zout + zoff) = o;
}

// ---------------------------------------------------------------------------
// p[row] = t[row,:] . W2   (one wave per row)
// ---------------------------------------------------------------------------
__global__ __launch_bounds__(256) void sem_p(const float* __restrict__ t,
                                             const float* __restrict__ W2,
                                             float* __restrict__ p, int Rows) {
  int row = blockIdx.x * 4 + (threadIdx.x >> 6);
  int lane = threadIdx.x & 63;
  if (row >= Rows) return;
  const float* tr = t + (size_t)row * SH;
  float v = tr[lane] * W2[lane] + tr[64 + lane] * W2[64 + lane];
#pragma unroll
  for (int s = 32; s > 0; s >>= 1) v += __shfl_xor(v, s, 64);
  if (lane == 0) p[row] = v;
}

// ---------------------------------------------------------------------------
// beta = softmax_m( sum_{b,n valid} p[b,n,m] / sum(node_nums) )  — 1 block
// ---------------------------------------------------------------------------
__global__ __launch_bounds__(256) void sem_beta(const float* __restrict__ p,
                                                const int* __restrict__ node_nums,
                                                float* __restrict__ beta) {
  __shared__ float red[256][M_];
  int tid = threadIdx.x;
  float loc[M_] = {};
  int nn0 = node_nums[0], nn1 = node_nums[1], nn2 = node_nums[2], nn3 = node_nums[3];
  for (int r = tid; r < B_ * N_ * M_; r += 256) {
    int m = r % M_;
    int bn = r / M_;
    int b = bn / N_, n = bn % N_;
    int nn = (b == 0) ? nn0 : (b == 1) ? nn1 : (b == 2) ? nn2 : nn3;
    if (n < nn) loc[m] += p[r];
  }
  for (int m = 0; m < M_; ++m) red[tid][m] = loc[m];
  __syncthreads();
  for (int st = 128; st > 0; st >>= 1) {
    if (tid < st)
      for (int m = 0; m < M_; ++m) red[tid][m] += red[tid + st][m];
    __syncthreads();
  }
  if (tid == 0) {
    float tot = (float)(nn0 + nn1 + nn2 + nn3);
    float w[M_], mx = -1e30f;
    for (int m = 0; m < M_; ++m) {
      w[m] = red[0][m] / tot;
      mx = fmaxf(mx, w[m]);
    }
    float s = 0.f;
    for (int m = 0; m < M_; ++m) {
      w[m] = __expf(w[m] - mx);
      s += w[m];
    }
    for (int m = 0; m < M_; ++m) beta[m] = w[m] / s;
  }
}

// ---------------------------------------------------------------------------
// h[b,n,hd] = sum_m beta[m] * z[b,n,m,hd]
// ---------------------------------------------------------------------------
__global__ __launch_bounds__(256) void sem_combine(const float* __restrict__ zb,
                                                   const float* __restrict__ beta,
                                                   float* __restrict__ hout) {
  int idx = blockIdx.x * 256 + threadIdx.x;
  int hd = idx & (HD - 1);
  int bn = idx >> 8;
  const float* zr = zb + (size_t)bn * M_ * HD + hd;
  float v = beta[0] * zr[0] + beta[1] * zr[HD] + beta[2] * zr[2 * HD] +
            beta[3] * zr[3 * HD] + beta[4] * zr[4 * HD];
  hout[idx] = v;
}

// ---------------------------------------------------------------------------
// logits = (h @ pred_W + pred_b) * nmask   (one wave per row)
// ---------------------------------------------------------------------------
__global__ __launch_bounds__(256) void pred_kernel(
    const float* __restrict__ h, const float* __restrict__ W,
    const float* __restrict__ bias, const int* __restrict__ node_nums,
    float* __restrict__ out) {
  int row = blockIdx.x * 4 + (threadIdx.x >> 6);
  int lane = threadIdx.x & 63;
  if (row >= B_ * N_) return;
  int b = row / N_, n = row % N_;
  const float* hr = h + (size_t)row * HD;
  float4 hv = *(const float4*)(hr + lane * 4);
  float res[OUTD];
#pragma unroll
  for (int o = 0; o < OUTD; ++o) {
    int k = lane * 4;
    float v = hv.x * W[(k + 0) * OUTD + o] + hv.y * W[(k + 1) * OUTD + o] +
              hv.z * W[(k + 2) * OUTD + o] + hv.w * W[(k + 3) * OUTD + o];
#pragma unroll
    for (int s = 32; s > 0; s >>= 1) v += __shfl_xor(v, s, 64);
    res[o] = v;
  }
  if (lane == 0) {
    float nm = (n < node_nums[b]) ? 1.f : 0.f;
#pragma unroll
    for (int o = 0; o < OUTD; ++o)
      out[(size_t)row * OUTD + o] = (res[o] + bias[o]) * nm;
  }
}

extern "C" void kernel_launch(void* const* d_in, const int* in_sizes, int n_in,
                              void* d_out, int out_size, void* d_ws, size_t ws_size,
                              hipStream_t stream) {
  const float* x = (const float*)d_in[0];
  const float* adj = (const float*)d_in[1];
  const int* node_nums = (const int*)d_in[2];
  const float* fc1 = (const float*)d_in[3];
  const float* al1 = (const float*)d_in[4];
  const float* ar1 = (const float*)d_in[5];
  const float* gb1 = (const float*)d_in[6];
  const float* sW1_1 = (const float*)d_in[7];
  const float* sb1_1 = (const float*)d_in[8];
  const float* sW2_1 = (const float*)d_in[9];
  const float* fc2 = (const float*)d_in[10];
  const float* al2 = (const float*)d_in[11];
  const float* ar2 = (const float*)d_in[12];
  const float* gb2 = (const float*)d_in[13];
  const float* sW1_2 = (const float*)d_in[14];
  const float* sb1_2 = (const float*)d_in[15];
  const float* sW2_2 = (const float*)d_in[16];
  const float* predW = (const float*)d_in[17];
  const float* predb = (const float*)d_in[18];
  float* out = (float*)d_out;

  char* ws = (char*)d_ws;
  size_t off = 0;
  unsigned long long* maskW = (unsigned long long*)(ws + off);
  off += (size_t)B_ * M_ * N_ * NW * 8;
  float* feat = (float*)(ws + off); off += (size_t)B_ * M_ * N_ * HD * 4;
  float* el = (float*)(ws + off); off += (size_t)B_ * M_ * N_ * H_ * 4;
  float* er = (float*)(ws + off); off += (size_t)B_ * M_ * N_ * H_ * 4;
  float* zb = (float*)(ws + off); off += (size_t)B_ * N_ * M_ * HD * 4;
  float* t = (float*)(ws + off); off += (size_t)B_ * N_ * M_ * SH * 4;
  float* p = (float*)(ws + off); off += (size_t)B_ * N_ * M_ * 4;
  float* h1 = (float*)(ws + off); off += (size_t)B_ * N_ * HD * 4;
  float* beta = (float*)(ws + off); off += 256;
  // bf16 hi/lo split buffers
  u16* xh = (u16*)(ws + off); off += (size_t)B_ * N_ * FIN * 2;
  u16* xl = (u16*)(ws + off); off += (size_t)B_ * N_ * FIN * 2;
  u16* fc1Th = (u16*)(ws + off); off += (size_t)M_ * HD * FIN * 2;
  u16* fc1Tl = (u16*)(ws + off); off += (size_t)M_ * HD * FIN * 2;
  u16* fc2Th = (u16*)(ws + off); off += (size_t)M_ * HD * HD * 2;
  u16* fc2Tl = (u16*)(ws + off); off += (size_t)M_ * HD * HD * 2;
  u16* sW1Th1 = (u16*)(ws + off); off += (size_t)SH * HD * 2;
  u16* sW1Tl1 = (u16*)(ws + off); off += (size_t)SH * HD * 2;
  u16* sW1Th2 = (u16*)(ws + off); off += (size_t)SH * HD * 2;
  u16* sW1Tl2 = (u16*)(ws + off); off += (size_t)SH * HD * 2;
  u16* h1h = (u16*)(ws + off); off += (size_t)B_ * N_ * HD * 2;
  u16* h1l = (u16*)(ws + off); off += (size_t)B_ * N_ * HD * 2;
  u16* zbh = (u16*)(ws + off); off += (size_t)B_ * N_ * M_ * HD * 2;
  u16* zbl = (u16*)(ws + off); off += (size_t)B_ * N_ * M_ * HD * 2;

  const int ROWS = B_ * N_ * M_;  // 20000

  build_maskbits<<<dim3(16, 16, B_ * M_), 256, 0, stream>>>(adj, node_nums, maskW);

  // ---- weight + input splits (layer-independent ones upfront) ----
  split_kernel<<<dim3((N_ * FIN / 4 + 255) / 256, 1, B_), 256, 0, stream>>>(
      x, (size_t)M_ * N_ * FIN, xh, xl, (size_t)N_ * FIN, N_ * FIN / 4);
  splitT_kernel<<<dim3(FIN / 32, HD / 32, M_), 256, 0, stream>>>(
      fc1, (size_t)FIN * HD, fc1Th, fc1Tl, (size_t)HD * FIN, FIN, HD);
  splitT_kernel<<<dim3(HD / 32, HD / 32, M_), 256, 0, stream>>>(
      fc2, (size_t)HD * HD, fc2Th, fc2Tl, (size_t)HD * HD, HD, HD);
  splitT_kernel<<<dim3(HD / 32, SH / 32, 1), 256, 0, stream>>>(
      sW1_1, 0, sW1Th1, sW1Tl1, 0, HD, SH);
  splitT_kernel<<<dim3(HD / 32, SH / 32, 1), 256, 0, stream>>>(
      sW1_2, 0, sW1Th2, sW1Tl2, 0, HD, SH);

  // ---- layer 1 ----
  gemm_mfma<<<dim3(16, HD / 64, B_ * M_), 256, 0, stream>>>(
      xh, xl, M_, (size_t)N_ * FIN, fc1Th, fc1Tl, (size_t)HD * FIN,
      feat, (size_t)N_ * HD, N_, FIN, HD, 0, nullptr);
  elr_kernel<<<dim3(16, M_, B_), 256, 0, stream>>>(feat, al1, ar1, el, er);
  gat_agg<<<dim3(ROWS / 4), 256, 0, stream>>>(maskW, feat, el, er, gb1, zb);
  split_kernel<<<dim3((ROWS * HD / 4 + 255) / 256, 1, 1), 256, 0, stream>>>(
      zb, 0, zbh, zbl, 0, ROWS * HD / 4);
  gemm_mfma<<<dim3((ROWS + 63) / 64, SH / 64, 1), 256, 0, stream>>>(
      zbh, zbl, 1, 0, sW1Th1, sW1Tl1, 0, t, 0, ROWS, HD, SH, 1, sb1_1);
  sem_p<<<dim3(ROWS / 4), 256, 0, stream>>>(t, sW2_1, p, ROWS);
  sem_beta<<<dim3(1), 256, 0, stream>>>(p, node_nums, beta);
  sem_combine<<<dim3(B_ * N_ * HD / 256), 256, 0, stream>>>(zb, beta, h1);
  split_kernel<<<dim3((B_ * N_ * HD / 4 + 255) / 256, 1, 1), 256, 0, stream>>>(
      h1, 0, h1h, h1l, 0, B_ * N_ * HD / 4);

  // ---- layer 2 ----
  gemm_mfma<<<dim3(16, HD / 64, B_ * M_), 256, 0, stream>>>(
      h1h, h1l, M_, (size_t)N_ * HD, fc2Th, fc2Tl, (size_t)HD * HD,
      feat, (size_t)N_ * HD, N_, HD, HD, 0, nullptr);
  elr_kernel<<<dim3(16, M_, B_), 256, 0, stream>>>(feat, al2, ar2, el, er);
  gat_agg<<<dim3(ROWS / 4), 256, 0, stream>>>(maskW, feat, el, er, gb2, zb);
  split_kernel<<<dim3((ROWS * HD / 4 + 255) / 256, 1, 1), 256, 0, stream>>>(
      zb, 0, zbh, zbl, 0, ROWS * HD / 4);
  gemm_mfma<<<dim3((ROWS + 63) / 64, SH / 64, 1), 256, 0, stream>>>(
      zbh, zbl, 1, 0, sW1Th2, sW1Tl2, 0, t, 0, ROWS, HD, SH, 1, sb1_2);
  sem_p<<<dim3(ROWS / 4), 256, 0, stream>>>(t, sW2_2, p, ROWS);
  sem_beta<<<dim3(1), 256, 0, stream>>>(p, node_nums, beta);
  sem_combine<<<dim3(B_ * N_ * HD / 256), 256, 0, stream>>>(zb, beta, h1);

  // ---- prediction head ----
  pred_kernel<<<dim3(B_ * N_ / 4), 256, 0, stream>>>(h1, predW, predb, node_nums, out);
}

// Round 4
// 217.104 us; speedup vs baseline: 1.9766x; 1.4746x over previous
//
#include <hip/hip_runtime.h>
#include <hip/hip_bf16.h>

#define B_ 4
#define M_ 5
#define N_ 1000
#define FIN 64
#define H_ 4
#define D_ 64
#define HD 256
#define SH 128
#define OUTD 5
#define NW 16  // u64 words per dest row (1024/64)
#define THRESH_ 0.97f

typedef unsigned short u16;
typedef u16 us8 __attribute__((ext_vector_type(8)));
typedef short s16x8 __attribute__((ext_vector_type(8)));
typedef float f32x4 __attribute__((ext_vector_type(4)));

__device__ inline u16 bf16_bits(float v) {
  __hip_bfloat16 h = __float2bfloat16(v);
  return *reinterpret_cast<u16*>(&h);
}
__device__ inline float bf16_val(u16 b) {
  __hip_bfloat16 h;
  *reinterpret_cast<u16*>(&h) = b;
  return __bfloat162float(h);
}
__device__ inline void split2(float v, u16& h, u16& l) {
  h = bf16_bits(v);
  l = bf16_bits(v - bf16_val(h));
}

// ---------------------------------------------------------------------------
// Build bit-packed transposed edge mask (shared by both layers).
// ---------------------------------------------------------------------------
__global__ __launch_bounds__(256) void build_maskbits(
    const float* __restrict__ adj, const int* __restrict__ node_nums,
    unsigned long long* __restrict__ maskW) {
  int bm = blockIdx.z;
  int b = bm / M_;
  int s0 = blockIdx.x * 64, d0 = blockIdx.y * 64;
  int nn = node_nums[b];
  __shared__ unsigned char tile[64][65];
  const float* arow = adj + (size_t)bm * N_ * N_;
  int tid = threadIdx.x;
#pragma unroll
  for (int k = 0; k < 16; ++k) {
    int idx = k * 256 + tid;
    int sl = idx >> 6, dl = idx & 63;
    int s = s0 + sl, d = d0 + dl;
    unsigned char v = 0;
    if (s < nn && d < nn && s < N_ && d < N_)
      v = (arow[(size_t)s * N_ + d] > THRESH_) ? 1 : 0;
    tile[sl][dl] = v;
  }
  __syncthreads();
  int w = tid >> 6, lane = tid & 63;
#pragma unroll
  for (int j = 0; j < 16; ++j) {
    int dl = w * 16 + j;
    bool act = tile[lane][dl] != 0;
    unsigned long long word = __ballot(act);
    int d = d0 + dl;
    if (lane == 0 && d < N_)
      maskW[((size_t)bm * N_ + d) * NW + blockIdx.x] = word;
  }
}

// ---------------------------------------------------------------------------
// Elementwise split fp32 -> bf16 hi + lo (z-batched, float4 vectorized).
// ---------------------------------------------------------------------------
__global__ __launch_bounds__(256) void split_kernel(
    const float* __restrict__ src, size_t sZ,
    u16* __restrict__ hi, u16* __restrict__ lo, size_t dZ, int n4) {
  int z = blockIdx.z;
  int i = blockIdx.x * 256 + threadIdx.x;
  if (i >= n4) return;
  const float4* s = (const float4*)(src + z * sZ);
  float4 v = s[i];
  ushort4 h, l;
  split2(v.x, h.x, l.x);
  split2(v.y, h.y, l.y);
  split2(v.z, h.z, l.z);
  split2(v.w, h.w, l.w);
  *(ushort4*)(hi + z * dZ + (size_t)i * 4) = h;
  *(ushort4*)(lo + z * dZ + (size_t)i * 4) = l;
}

// ---------------------------------------------------------------------------
// Transpose + split: src (K x N) fp32  ->  dst (N x K) bf16 hi/lo (z-batched).
// ---------------------------------------------------------------------------
__global__ __launch_bounds__(256) void splitT_kernel(
    const float* __restrict__ src, size_t sZ,
    u16* __restrict__ hiT, u16* __restrict__ loT, size_t dZ, int K, int N) {
  int z = blockIdx.z;
  const float* s = src + z * sZ;
  int k0 = blockIdx.x * 32, n0 = blockIdx.y * 32;
  __shared__ float tile[32][33];
  int tid = threadIdx.x;
  int kl = tid >> 3, nq = (tid & 7) * 4;
  *(float4*)&tile[kl][nq] = *(const float4*)(s + (size_t)(k0 + kl) * N + n0 + nq);
  __syncthreads();
  int nl = tid >> 3, kq = (tid & 7) * 4;
  ushort4 h, l;
  split2(tile[kq + 0][nl], h.x, l.x);
  split2(tile[kq + 1][nl], h.y, l.y);
  split2(tile[kq + 2][nl], h.z, l.z);
  split2(tile[kq + 3][nl], h.w, l.w);
  size_t o = z * dZ + (size_t)(n0 + nl) * K + k0 + kq;
  *(ushort4*)(hiT + o) = h;
  *(ushort4*)(loT + o) = l;
}

// ---------------------------------------------------------------------------
// Split-bf16 MFMA GEMM (feat): C[z] = A[z] @ B[z]^T-stored. 3 mfma/product
// (hh + hl + lh) for fp32-grade accuracy. 64x64 tile, 4 waves, 2x2 16x16x32.
// ---------------------------------------------------------------------------
__global__ __launch_bounds__(256) void gemm_mfma3(
    const u16* __restrict__ Ah, const u16* __restrict__ Al, int Mz, size_t aZ,
    const u16* __restrict__ Bh, const u16* __restrict__ Bl, size_t bZ,
    float* __restrict__ C, size_t cZ, int Mrows, int K, int Nc) {
  __shared__ u16 sAh[64][40], sAl[64][40], sBh[64][40], sBl[64][40];
  int z = blockIdx.z;
  const u16* Ahb = Ah + (size_t)(z / Mz) * aZ;
  const u16* Alb = Al + (size_t)(z / Mz) * aZ;
  const u16* Bhb = Bh + (size_t)(z % Mz) * bZ;
  const u16* Blb = Bl + (size_t)(z % Mz) * bZ;
  float* Cb = C + (size_t)z * cZ;
  int row0 = blockIdx.x * 64, col0 = blockIdx.y * 64;
  int tid = threadIdx.x;
  int arow = tid >> 2, akq = (tid & 3) * 8;
  int wid = tid >> 6, lane = tid & 63;
  int wr = (wid >> 1) * 32, wc = (wid & 1) * 32;
  int lrow = lane & 15, kseg = (lane >> 4) * 8;
  f32x4 zero4 = {0.f, 0.f, 0.f, 0.f};
  f32x4 acc[2][2];
  acc[0][0] = zero4; acc[0][1] = zero4; acc[1][0] = zero4; acc[1][1] = zero4;
  for (int k0 = 0; k0 < K; k0 += 32) {
    us8 av = {0, 0, 0, 0, 0, 0, 0, 0}, alv = av;
    int gr = row0 + arow;
    if (gr < Mrows) {
      av = *(const us8*)(Ahb + (size_t)gr * K + k0 + akq);
      alv = *(const us8*)(Alb + (size_t)gr * K + k0 + akq);
    }
    *(us8*)&sAh[arow][akq] = av;
    *(us8*)&sAl[arow][akq] = alv;
    us8 bv = *(const us8*)(Bhb + (size_t)(col0 + arow) * K + k0 + akq);
    us8 blv = *(const us8*)(Blb + (size_t)(col0 + arow) * K + k0 + akq);
    *(us8*)&sBh[arow][akq] = bv;
    *(us8*)&sBl[arow][akq] = blv;
    __syncthreads();
    s16x8 aH[2], aL[2], bH[2], bL[2];
#pragma unroll
    for (int i = 0; i < 2; ++i) {
      aH[i] = *(const s16x8*)&sAh[wr + 16 * i + lrow][kseg];
      aL[i] = *(const s16x8*)&sAl[wr + 16 * i + lrow][kseg];
      bH[i] = *(const s16x8*)&sBh[wc + 16 * i + lrow][kseg];
      bL[i] = *(const s16x8*)&sBl[wc + 16 * i + lrow][kseg];
    }
#pragma unroll
    for (int i = 0; i < 2; ++i)
#pragma unroll
      for (int j = 0; j < 2; ++j) {
        acc[i][j] = __builtin_amdgcn_mfma_f32_16x16x32_bf16(aH[i], bH[j], acc[i][j], 0, 0, 0);
        acc[i][j] = __builtin_amdgcn_mfma_f32_16x16x32_bf16(aH[i], bL[j], acc[i][j], 0, 0, 0);
        acc[i][j] = __builtin_amdgcn_mfma_f32_16x16x32_bf16(aL[i], bH[j], acc[i][j], 0, 0, 0);
      }
    __syncthreads();
  }
#pragma unroll
  for (int i = 0; i < 2; ++i)
#pragma unroll
    for (int j = 0; j < 2; ++j) {
      int ccol = col0 + wc + 16 * j + lrow;
#pragma unroll
      for (int r = 0; r < 4; ++r) {
        int crow = row0 + wr + 16 * i + (lane >> 4) * 4 + r;
        if (crow < Mrows) Cb[(size_t)crow * Nc + ccol] = acc[i][j][r];
      }
    }
}

// ---------------------------------------------------------------------------
// Semantic GEMM fused: p[row] += sum_col tanh(A@W1 + b1)[row,col] * W2[col].
// A bf16-only (1 mfma). Epilogue: 16-lane shuffle reduce + atomicAdd into p.
// p must be zeroed beforehand (done in elr_kernel).
// ---------------------------------------------------------------------------
__global__ __launch_bounds__(256) void gemm_sem(
    const u16* __restrict__ Ah, const u16* __restrict__ Bh,
    const float* __restrict__ bias, const float* __restrict__ W2,
    float* __restrict__ p, int Mrows) {
  __shared__ u16 sA[64][40], sB[64][40];
  int row0 = blockIdx.x * 64, col0 = blockIdx.y * 64;
  int tid = threadIdx.x;
  int arow = tid >> 2, akq = (tid & 3) * 8;
  int wid = tid >> 6, lane = tid & 63;
  int wr = (wid >> 1) * 32, wc = (wid & 1) * 32;
  int lrow = lane & 15, kseg = (lane >> 4) * 8;
  f32x4 zero4 = {0.f, 0.f, 0.f, 0.f};
  f32x4 acc[2][2];
  acc[0][0] = zero4; acc[0][1] = zero4; acc[1][0] = zero4; acc[1][1] = zero4;
  for (int k0 = 0; k0 < HD; k0 += 32) {
    us8 av = {0, 0, 0, 0, 0, 0, 0, 0};
    int gr = row0 + arow;
    if (gr < Mrows) av = *(const us8*)(Ah + (size_t)gr * HD + k0 + akq);
    *(us8*)&sA[arow][akq] = av;
    us8 bv = *(const us8*)(Bh + (size_t)(col0 + arow) * HD + k0 + akq);
    *(us8*)&sB[arow][akq] = bv;
    __syncthreads();
    s16x8 aH[2], bH[2];
#pragma unroll
    for (int i = 0; i < 2; ++i) {
      aH[i] = *(const s16x8*)&sA[wr + 16 * i + lrow][kseg];
      bH[i] = *(const s16x8*)&sB[wc + 16 * i + lrow][kseg];
    }
#pragma unroll
    for (int i = 0; i < 2; ++i)
#pragma unroll
      for (int j = 0; j < 2; ++j)
        acc[i][j] = __builtin_amdgcn_mfma_f32_16x16x32_bf16(aH[i], bH[j], acc[i][j], 0, 0, 0);
    __syncthreads();
  }
#pragma unroll
  for (int i = 0; i < 2; ++i) {
#pragma unroll
    for (int r = 0; r < 4; ++r) {
      float part = 0.f;
#pragma unroll
      for (int j = 0; j < 2; ++j) {
        int ccol = col0 + wc + 16 * j + lrow;
        float v = tanhf(acc[i][j][r] + bias[ccol]);
        part += v * W2[ccol];
      }
#pragma unroll
      for (int s = 1; s < 16; s <<= 1) part += __shfl_xor(part, s, 64);
      int crow = row0 + wr + 16 * i + (lane >> 4) * 4 + r;
      if (lrow == 0 && crow < Mrows) atomicAdd(&p[crow], part);
    }
  }
}

// ---------------------------------------------------------------------------
// el/er: wave-per-row, 16-lane reduce per head. Also zeroes p for gemm_sem.
// ---------------------------------------------------------------------------
__global__ __launch_bounds__(256) void elr_kernel(
    const float* __restrict__ feat, const float* __restrict__ al,
    const float* __restrict__ ar, float* __restrict__ el,
    float* __restrict__ er, float* __restrict__ p) {
  int b = blockIdx.z, m = blockIdx.y;
  int wid = threadIdx.x >> 6, lane = threadIdx.x & 63;
  if (blockIdx.y == 0 && blockIdx.z == 0) {
    int idx = blockIdx.x * 256 + threadIdx.x;
    if (idx < B_ * N_ * M_) p[idx] = 0.f;
  }
  int n = blockIdx.x * 4 + wid;
  size_t bmN = (size_t)(b * M_ + m) * N_;
  float4 f = *(const float4*)(feat + (bmN + n) * HD + lane * 4);
  float4 a4 = *(const float4*)(al + m * HD + lane * 4);
  float4 r4 = *(const float4*)(ar + m * HD + lane * 4);
  float vl = f.x * a4.x + f.y * a4.y + f.z * a4.z + f.w * a4.w;
  float vr = f.x * r4.x + f.y * r4.y + f.z * r4.z + f.w * r4.w;
#pragma unroll
  for (int s = 1; s < 16; s <<= 1) {
    vl += __shfl_xor(vl, s, 64);
    vr += __shfl_xor(vr, s, 64);
  }
  if ((lane & 15) == 0) {
    int h = lane >> 4;
    el[(bmN + n) * H_ + h] = vl;
    er[(bmN + n) * H_ + h] = vr;
  }
}

// ---------------------------------------------------------------------------
// GAT aggregation: one wave per destination, barrier-free. Direct exp
// (no max subtraction — logits bounded by construction, |v| << 80).
// Writes zb fp32 AND zbh bf16 (fused split for the semantic GEMM).
// ---------------------------------------------------------------------------
__global__ __launch_bounds__(256) void gat_agg(
    const unsigned long long* __restrict__ maskW, const float* __restrict__ feat,
    const float* __restrict__ el, const float* __restrict__ er,
    const float* __restrict__ gb, float* __restrict__ zout,
    u16* __restrict__ zbh) {
  int wid = threadIdx.x >> 6, lane = threadIdx.x & 63;
  int gw = blockIdx.x * 4 + wid;
  int d = gw % N_, bm = gw / N_;
  int m = bm % M_, b = bm / M_;
  __shared__ int slist_all[4][1024];
  int* slist = slist_all[wid];

  const unsigned long long* mrow = maskW + ((size_t)bm * N_ + d) * NW;
  int cnt = 0;
#pragma unroll
  for (int w16 = 0; w16 < NW; ++w16) {
    unsigned long long word = mrow[w16];
    if (word) {
      if ((word >> lane) & 1ull) {
        int pos = cnt + (int)__popcll(word & ((1ull << lane) - 1ull));
        slist[pos] = w16 * 64 + lane;
      }
      cnt += (int)__popcll(word);
    }
  }

  int h = lane >> 4;
  float4 bias = *(const float4*)(gb + m * HD + lane * 4);
  size_t zoff = ((size_t)(b * N_ + d) * M_ + m) * HD + lane * 4;
  float4 o;
  if (cnt == 0) {
    o.x = bias.x > 0.f ? bias.x : (__expf(bias.x) - 1.f);
    o.y = bias.y > 0.f ? bias.y : (__expf(bias.y) - 1.f);
    o.z = bias.z > 0.f ? bias.z : (__expf(bias.z) - 1.f);
    o.w = bias.w > 0.f ? bias.w : (__expf(bias.w) - 1.f);
  } else {
    size_t bmN = (size_t)bm * N_;
    float erv = er[(bmN + d) * H_ + h];
    const float* elb = el + bmN * H_;
    const float* fb = feat + bmN * HD;
    float den = 0.f, ax = 0.f, ay = 0.f, az = 0.f, aw = 0.f;
    for (int i = 0; i < cnt; ++i) {
      int s = slist[i];
      float v = elb[(size_t)s * H_ + h] + erv;
      v = v > 0.f ? v : 0.2f * v;  // leaky_relu
      float w = __expf(v);         // no max: mathematically identical softmax
      float4 f = *(const float4*)(fb + (size_t)s * HD + lane * 4);
      den += w;
      ax += w * f.x;
      ay += w * f.y;
      az += w * f.z;
      aw += w * f.w;
    }
    float inv = 1.f / den;
    float vx = ax * inv + bias.x;
    float vy = ay * inv + bias.y;
    float vz = az * inv + bias.z;
    float vw = aw * inv + bias.w;
    o.x = vx > 0.f ? vx : (__expf(vx) - 1.f);
    o.y = vy > 0.f ? vy : (__expf(vy) - 1.f);
    o.z = vz > 0.f ? vz : (__expf(vz) - 1.f);
    o.w = vw > 0.f ? vw : (__expf(vw) - 1.f);
  }
  *(float4*)(zout + zoff) = o;
  ushort4 hh;
  hh.x = bf16_bits(o.x);
  hh.y = bf16_bits(o.y);
  hh.z = bf16_bits(o.z);
  hh.w = bf16_bits(o.w);
  *(ushort4*)(zbh + zoff) = hh;
}

// ---------------------------------------------------------------------------
// beta = softmax_m( sum_{b,n valid} p[b,n,m] / sum(node_nums) )  — 1 block
// ---------------------------------------------------------------------------
__global__ __launch_bounds__(256) void sem_beta(const float* __restrict__ p,
                                                const int* __restrict__ node_nums,
                                                float* __restrict__ beta) {
  __shared__ float red[256][M_];
  int tid = threadIdx.x;
  float loc[M_] = {};
  int nn0 = node_nums[0], nn1 = node_nums[1], nn2 = node_nums[2], nn3 = node_nums[3];
  for (int r = tid; r < B_ * N_ * M_; r += 256) {
    int m = r % M_;
    int bn = r / M_;
    int b = bn / N_, n = bn % N_;
    int nn = (b == 0) ? nn0 : (b == 1) ? nn1 : (b == 2) ? nn2 : nn3;
    if (n < nn) loc[m] += p[r];
  }
  for (int m = 0; m < M_; ++m) red[tid][m] = loc[m];
  __syncthreads();
  for (int st = 128; st > 0; st >>= 1) {
    if (tid < st)
      for (int m = 0; m < M_; ++m) red[tid][m] += red[tid + st][m];
    __syncthreads();
  }
  if (tid == 0) {
    float tot = (float)(nn0 + nn1 + nn2 + nn3);
    float w[M_], mx = -1e30f;
    for (int m = 0; m < M_; ++m) {
      w[m] = red[0][m] / tot;
      mx = fmaxf(mx, w[m]);
    }
    float s = 0.f;
    for (int m = 0; m < M_; ++m) {
      w[m] = __expf(w[m] - mx);
      s += w[m];
    }
    for (int m = 0; m < M_; ++m) beta[m] = w[m] / s;
  }
}

// ---------------------------------------------------------------------------
// Layer-1 combine: h = sum_m beta[m]*z, written directly as bf16 hi/lo.
// ---------------------------------------------------------------------------
__global__ __launch_bounds__(256) void sem_combine_split(
    const float* __restrict__ zb, const float* __restrict__ beta,
    u16* __restrict__ hh, u16* __restrict__ hl) {
  int idx = blockIdx.x * 256 + threadIdx.x;
  int hd = idx & (HD - 1);
  int bn = idx >> 8;
  const float* zr = zb + (size_t)bn * M_ * HD + hd;
  float v = beta[0] * zr[0] + beta[1] * zr[HD] + beta[2] * zr[2 * HD] +
            beta[3] * zr[3 * HD] + beta[4] * zr[4 * HD];
  u16 h, l;
  split2(v, h, l);
  hh[idx] = h;
  hl[idx] = l;
}

// ---------------------------------------------------------------------------
// Layer-2 combine fused with prediction head: one wave per row.
// logits = ((sum_m beta_m z_m) @ predW + predb) * nmask
// ---------------------------------------------------------------------------
__global__ __launch_bounds__(256) void sem_combine_pred(
    const float* __restrict__ zb, const float* __restrict__ beta,
    const float* __restrict__ W, const float* __restrict__ bias,
    const int* __restrict__ node_nums, float* __restrict__ out) {
  int row = blockIdx.x * 4 + (threadIdx.x >> 6);
  int lane = threadIdx.x & 63;
  int b = row / N_, n = row % N_;
  const float* zr = zb + (size_t)row * M_ * HD + lane * 4;
  float b0 = beta[0], b1 = beta[1], b2 = beta[2], b3 = beta[3], b4 = beta[4];
  float4 z0 = *(const float4*)(zr);
  float4 z1 = *(const float4*)(zr + HD);
  float4 z2 = *(const float4*)(zr + 2 * HD);
  float4 z3 = *(const float4*)(zr + 3 * HD);
  float4 z4 = *(const float4*)(zr + 4 * HD);
  float hx = b0 * z0.x + b1 * z1.x + b2 * z2.x + b3 * z3.x + b4 * z4.x;
  float hy = b0 * z0.y + b1 * z1.y + b2 * z2.y + b3 * z3.y + b4 * z4.y;
  float hz = b0 * z0.z + b1 * z1.z + b2 * z2.z + b3 * z3.z + b4 * z4.z;
  float hw = b0 * z0.w + b1 * z1.w + b2 * z2.w + b3 * z3.w + b4 * z4.w;
  int k = lane * 4;
  float res[OUTD];
#pragma unroll
  for (int o = 0; o < OUTD; ++o) {
    float v = hx * W[(k + 0) * OUTD + o] + hy * W[(k + 1) * OUTD + o] +
              hz * W[(k + 2) * OUTD + o] + hw * W[(k + 3) * OUTD + o];
#pragma unroll
    for (int s = 1; s < 64; s <<= 1) v += __shfl_xor(v, s, 64);
    res[o] = v;
  }
  if (lane == 0) {
    float nm = (n < node_nums[b]) ? 1.f : 0.f;
#pragma unroll
    for (int o = 0; o < OUTD; ++o)
      out[(size_t)row * OUTD + o] = (res[o] + bias[o]) * nm;
  }
}

extern "C" void kernel_launch(void* const* d_in, const int* in_sizes, int n_in,
                              void* d_out, int out_size, void* d_ws, size_t ws_size,
                              hipStream_t stream) {
  const float* x = (const float*)d_in[0];
  const float* adj = (const float*)d_in[1];
  const int* node_nums = (const int*)d_in[2];
  const float* fc1 = (const float*)d_in[3];
  const float* al1 = (const float*)d_in[4];
  const float* ar1 = (const float*)d_in[5];
  const float* gb1 = (const float*)d_in[6];
  const float* sW1_1 = (const float*)d_in[7];
  const float* sb1_1 = (const float*)d_in[8];
  const float* sW2_1 = (const float*)d_in[9];
  const float* fc2 = (const float*)d_in[10];
  const float* al2 = (const float*)d_in[11];
  const float* ar2 = (const float*)d_in[12];
  const float* gb2 = (const float*)d_in[13];
  const float* sW1_2 = (const float*)d_in[14];
  const float* sb1_2 = (const float*)d_in[15];
  const float* sW2_2 = (const float*)d_in[16];
  const float* predW = (const float*)d_in[17];
  const float* predb = (const float*)d_in[18];
  float* out = (float*)d_out;

  char* ws = (char*)d_ws;
  size_t off = 0;
  unsigned long long* maskW = (unsigned long long*)(ws + off);
  off += (size_t)B_ * M_ * N_ * NW * 8;
  float* feat = (float*)(ws + off); off += (size_t)B_ * M_ * N_ * HD * 4;
  float* el = (float*)(ws + off); off += (size_t)B_ * M_ * N_ * H_ * 4;
  float* er = (float*)(ws + off); off += (size_t)B_ * M_ * N_ * H_ * 4;
  float* zb = (float*)(ws + off); off += (size_t)B_ * N_ * M_ * HD * 4;
  float* p = (float*)(ws + off); off += (size_t)B_ * N_ * M_ * 4;
  float* beta = (float*)(ws + off); off += 256;
  u16* xh = (u16*)(ws + off); off += (size_t)B_ * N_ * FIN * 2;
  u16* xl = (u16*)(ws + off); off += (size_t)B_ * N_ * FIN * 2;
  u16* fc1Th = (u16*)(ws + off); off += (size_t)M_ * HD * FIN * 2;
  u16* fc1Tl = (u16*)(ws + off); off += (size_t)M_ * HD * FIN * 2;
  u16* fc2Th = (u16*)(ws + off); off += (size_t)M_ * HD * HD * 2;
  u16* fc2Tl = (u16*)(ws + off); off += (size_t)M_ * HD * HD * 2;
  u16* sW1Th1 = (u16*)(ws + off); off += (size_t)SH * HD * 2;
  u16* sW1Tl1 = (u16*)(ws + off); off += (size_t)SH * HD * 2;
  u16* sW1Th2 = (u16*)(ws + off); off += (size_t)SH * HD * 2;
  u16* sW1Tl2 = (u16*)(ws + off); off += (size_t)SH * HD * 2;
  u16* h1h = (u16*)(ws + off); off += (size_t)B_ * N_ * HD * 2;
  u16* h1l = (u16*)(ws + off); off += (size_t)B_ * N_ * HD * 2;
  u16* zbh = (u16*)(ws + off); off += (size_t)B_ * N_ * M_ * HD * 2;

  const int ROWS = B_ * N_ * M_;  // 20000

  build_maskbits<<<dim3(16, 16, B_ * M_), 256, 0, stream>>>(adj, node_nums, maskW);

  // ---- weight + input splits ----
  split_kernel<<<dim3((N_ * FIN / 4 + 255) / 256, 1, B_), 256, 0, stream>>>(
      x, (size_t)M_ * N_ * FIN, xh, xl, (size_t)N_ * FIN, N_ * FIN / 4);
  splitT_kernel<<<dim3(FIN / 32, HD / 32, M_), 256, 0, stream>>>(
      fc1, (size_t)FIN * HD, fc1Th, fc1Tl, (size_t)HD * FIN, FIN, HD);
  splitT_kernel<<<dim3(HD / 32, HD / 32, M_), 256, 0, stream>>>(
      fc2, (size_t)HD * HD, fc2Th, fc2Tl, (size_t)HD * HD, HD, HD);
  splitT_kernel<<<dim3(HD / 32, SH / 32, 1), 256, 0, stream>>>(
      sW1_1, 0, sW1Th1, sW1Tl1, 0, HD, SH);
  splitT_kernel<<<dim3(HD / 32, SH / 32, 1), 256, 0, stream>>>(
      sW1_2, 0, sW1Th2, sW1Tl2, 0, HD, SH);

  // ---- layer 1 ----
  gemm_mfma3<<<dim3(16, HD / 64, B_ * M_), 256, 0, stream>>>(
      xh, xl, M_, (size_t)N_ * FIN, fc1Th, fc1Tl, (size_t)HD * FIN,
      feat, (size_t)N_ * HD, N_, FIN, HD);
  elr_kernel<<<dim3(N_ / 4, M_, B_), 256, 0, stream>>>(feat, al1, ar1, el, er, p);
  gat_agg<<<dim3(ROWS / 4), 256, 0, stream>>>(maskW, feat, el, er, gb1, zb, zbh);
  gemm_sem<<<dim3((ROWS + 63) / 64, SH / 64, 1), 256, 0, stream>>>(
      zbh, sW1Th1, sb1_1, sW2_1, p, ROWS);
  sem_beta<<<dim3(1), 256, 0, stream>>>(p, node_nums, beta);
  sem_combine_split<<<dim3(B_ * N_ * HD / 256), 256, 0, stream>>>(zb, beta, h1h, h1l);

  // ---- layer 2 ----
  gemm_mfma3<<<dim3(16, HD / 64, B_ * M_), 256, 0, stream>>>(
      h1h, h1l, M_, (size_t)N_ * HD, fc2Th, fc2Tl, (size_t)HD * HD,
      feat, (size_t)N_ * HD, N_, HD, HD);
  elr_kernel<<<dim3(N_ / 4, M_, B_), 256, 0, stream>>>(feat, al2, ar2, el, er, p);
  gat_agg<<<dim3(ROWS / 4), 256, 0, stream>>>(maskW, feat, el, er, gb2, zb, zbh);
  gemm_sem<<<dim3((ROWS + 63) / 64, SH / 64, 1), 256, 0, stream>>>(
      zbh, sW1Th2, sb1_2, sW2_2, p, ROWS);
  sem_beta<<<dim3(1), 256, 0, stream>>>(p, node_nums, beta);
  sem_combine_pred<<<dim3(B_ * N_ / 4), 256, 0, stream>>>(
      zb, beta, predW, predb, node_nums, out);
}